// Round 1
// baseline (2881.356 us; speedup 1.0000x reference)
//
#include <hip/hip_runtime.h>

#define ND 32
#define ED 8
#define NL 4
#define NG 1000

// ---------- init kernels ----------

__global__ void k_init_h(const float* __restrict__ x,
                         const float* __restrict__ W,  // [2][ND]
                         const float* __restrict__ b,  // [ND]
                         float* __restrict__ h, int N) {
  int i = blockIdx.x * blockDim.x + threadIdx.x;
  if (i >= N * ND) return;
  int n = i >> 5, d = i & (ND - 1);
  h[i] = fmaf(x[2 * n], W[d], fmaf(x[2 * n + 1], W[ND + d], b[d]));
}

__global__ void k_init_e(const float* __restrict__ ea,
                         const float* __restrict__ W,  // [1][ED]
                         const float* __restrict__ b,  // [ED]
                         float* __restrict__ e, int E) {
  int i = blockIdx.x * blockDim.x + threadIdx.x;
  if (i >= E * ED) return;
  int ed = i >> 3, d = i & (ED - 1);
  e[i] = fmaf(ea[ed], W[d], b[d]);
}

// ---------- layer kernels ----------

__device__ __forceinline__ void acc4_ed(float4 v, const float* __restrict__ w,
                                        float* acc) {
#pragma unroll
  for (int j = 0; j < ED; ++j) acc[j] = fmaf(v.x, w[j], acc[j]);
#pragma unroll
  for (int j = 0; j < ED; ++j) acc[j] = fmaf(v.y, w[ED + j], acc[j]);
#pragma unroll
  for (int j = 0; j < ED; ++j) acc[j] = fmaf(v.z, w[2 * ED + j], acc[j]);
#pragma unroll
  for (int j = 0; j < ED; ++j) acc[j] = fmaf(v.w, w[3 * ED + j], acc[j]);
}

__device__ __forceinline__ void acc4_nd(float4 v, const float* __restrict__ w,
                                        float* acc) {
#pragma unroll
  for (int j = 0; j < ND; ++j) acc[j] = fmaf(v.x, w[j], acc[j]);
#pragma unroll
  for (int j = 0; j < ND; ++j) acc[j] = fmaf(v.y, w[ND + j], acc[j]);
#pragma unroll
  for (int j = 0; j < ND; ++j) acc[j] = fmaf(v.z, w[2 * ND + j], acc[j]);
#pragma unroll
  for (int j = 0; j < ND; ++j) acc[j] = fmaf(v.w, w[3 * ND + j], acc[j]);
}

// edge MLP: new_e = relu([h_src, h_dst, e] @ W + b); agg[dst]+=new_e; e+=new_e
__global__ void k_edge(const float* __restrict__ h,
                       float* __restrict__ e,
                       const int* __restrict__ src,
                       const int* __restrict__ dst,
                       const float* __restrict__ W,  // [(2*ND+ED)][ED]
                       const float* __restrict__ b,  // [ED]
                       float* __restrict__ agg,      // [N][ED]
                       int E) {
  __shared__ float sW[(2 * ND + ED) * ED];
  __shared__ float sb[ED];
  for (int i = threadIdx.x; i < (2 * ND + ED) * ED; i += blockDim.x) sW[i] = W[i];
  if (threadIdx.x < ED) sb[threadIdx.x] = b[threadIdx.x];
  __syncthreads();
  int i = blockIdx.x * blockDim.x + threadIdx.x;
  if (i >= E) return;
  int s = src[i], d = dst[i];
  float acc[ED];
#pragma unroll
  for (int j = 0; j < ED; ++j) acc[j] = sb[j];
  const float4* hs4 = reinterpret_cast<const float4*>(h + (size_t)s * ND);
  const float4* hd4 = reinterpret_cast<const float4*>(h + (size_t)d * ND);
#pragma unroll
  for (int q = 0; q < ND / 4; ++q) acc4_ed(hs4[q], &sW[q * 4 * ED], acc);
#pragma unroll
  for (int q = 0; q < ND / 4; ++q) acc4_ed(hd4[q], &sW[(ND + q * 4) * ED], acc);
  float4* e4 = reinterpret_cast<float4*>(e + (size_t)i * ED);
  float4 e0 = e4[0], e1 = e4[1];
  acc4_ed(e0, &sW[2 * ND * ED], acc);
  acc4_ed(e1, &sW[(2 * ND + 4) * ED], acc);
#pragma unroll
  for (int j = 0; j < ED; ++j) acc[j] = fmaxf(acc[j], 0.0f);
  float* ag = agg + (size_t)d * ED;
#pragma unroll
  for (int j = 0; j < ED; ++j) atomicAdd(&ag[j], acc[j]);
  float4 o0 = make_float4(e0.x + acc[0], e0.y + acc[1], e0.z + acc[2], e0.w + acc[3]);
  float4 o1 = make_float4(e1.x + acc[4], e1.y + acc[5], e1.z + acc[6], e1.w + acc[7]);
  e4[0] = o0;
  e4[1] = o1;
}

// node MLP: h += relu([h, agg] @ W + b)
__global__ void k_node(float* __restrict__ h,
                       const float* __restrict__ agg,
                       const float* __restrict__ W,  // [(ND+ED)][ND]
                       const float* __restrict__ b,  // [ND]
                       int N) {
  __shared__ float sW[(ND + ED) * ND];
  __shared__ float sb[ND];
  for (int i = threadIdx.x; i < (ND + ED) * ND; i += blockDim.x) sW[i] = W[i];
  if (threadIdx.x < ND) sb[threadIdx.x] = b[threadIdx.x];
  __syncthreads();
  int n = blockIdx.x * blockDim.x + threadIdx.x;
  if (n >= N) return;
  float acc[ND];
#pragma unroll
  for (int j = 0; j < ND; ++j) acc[j] = sb[j];
  float4* h4 = reinterpret_cast<float4*>(h + (size_t)n * ND);
  float4 hv[ND / 4];
#pragma unroll
  for (int q = 0; q < ND / 4; ++q) {
    hv[q] = h4[q];
    acc4_nd(hv[q], &sW[q * 4 * ND], acc);
  }
  const float4* a4 = reinterpret_cast<const float4*>(agg + (size_t)n * ED);
#pragma unroll
  for (int q = 0; q < ED / 4; ++q) acc4_nd(a4[q], &sW[(ND + q * 4) * ND], acc);
#pragma unroll
  for (int q = 0; q < ND / 4; ++q) {
    float4 o;
    o.x = hv[q].x + fmaxf(acc[q * 4 + 0], 0.0f);
    o.y = hv[q].y + fmaxf(acc[q * 4 + 1], 0.0f);
    o.z = hv[q].z + fmaxf(acc[q * 4 + 2], 0.0f);
    o.w = hv[q].w + fmaxf(acc[q * 4 + 3], 0.0f);
    h4[q] = o;
  }
}

// ---------- readout ----------

__device__ __forceinline__ unsigned int enc_f32(float f) {
  unsigned int bits = __float_as_uint(f);
  return (bits & 0x80000000u) ? ~bits : (bits | 0x80000000u);
}
__device__ __forceinline__ float dec_f32(unsigned int u) {
  unsigned int bits = (u & 0x80000000u) ? (u ^ 0x80000000u) : ~u;
  return __uint_as_float(bits);
}

__global__ void k_logits(const float* __restrict__ h,
                         const int* __restrict__ cand,
                         const int* __restrict__ batch,
                         const float* __restrict__ Wout,  // [ND]
                         const float* __restrict__ bout,  // [1]
                         float* __restrict__ logits,
                         int* __restrict__ seg,
                         unsigned int* __restrict__ mxu,  // [NG], pre-zeroed
                         int NC) {
  __shared__ float sW[ND];
  if (threadIdx.x < ND) sW[threadIdx.x] = Wout[threadIdx.x];
  __syncthreads();
  int c = blockIdx.x * blockDim.x + threadIdx.x;
  if (c >= NC) return;
  int idx = cand[c];
  const float* hr = h + (size_t)idx * ND;
  float acc = bout[0];
#pragma unroll
  for (int k = 0; k < ND; ++k) acc = fmaf(hr[k], sW[k], acc);
  logits[c] = acc;
  int g = batch[idx];
  seg[c] = g;
  atomicMax(&mxu[g], enc_f32(acc));
}

__global__ void k_expsum(float* __restrict__ logits,  // in: logits, out: shifted
                         const int* __restrict__ seg,
                         const unsigned int* __restrict__ mxu,
                         float* __restrict__ sum,  // [NG], pre-zeroed
                         int NC) {
  int c = blockIdx.x * blockDim.x + threadIdx.x;
  if (c >= NC) return;
  int g = seg[c];
  float m = dec_f32(mxu[g]);
  float sh = logits[c] - m;
  logits[c] = sh;
  atomicAdd(&sum[g], __expf(sh) * 0.0f + expf(sh));
}

__global__ void k_final(const float* __restrict__ shifted,
                        const int* __restrict__ seg,
                        const float* __restrict__ sum,
                        float* __restrict__ out, int NC) {
  int c = blockIdx.x * blockDim.x + threadIdx.x;
  if (c >= NC) return;
  out[c] = shifted[c] - logf(sum[seg[c]]);
}

// ---------- launch ----------

extern "C" void kernel_launch(void* const* d_in, const int* in_sizes, int n_in,
                              void* d_out, int out_size, void* d_ws, size_t ws_size,
                              hipStream_t stream) {
  const float* x       = (const float*)d_in[0];
  const float* ea      = (const float*)d_in[1];
  const float* Wn_in   = (const float*)d_in[2];
  const float* bn_in   = (const float*)d_in[3];
  const float* We_in   = (const float*)d_in[4];
  const float* be_in   = (const float*)d_in[5];
  const float* We_l    = (const float*)d_in[6];
  const float* be_l    = (const float*)d_in[7];
  const float* Wn_l    = (const float*)d_in[8];
  const float* bn_l    = (const float*)d_in[9];
  const float* Wout    = (const float*)d_in[10];
  const float* bout    = (const float*)d_in[11];
  const int* edge_index= (const int*)d_in[12];
  const int* batch     = (const int*)d_in[13];
  const int* cand      = (const int*)d_in[14];

  const int N  = in_sizes[13];
  const int E  = in_sizes[1];
  const int NC = in_sizes[14];

  char* ws = (char*)d_ws;
  float* h      = (float*)ws; ws += (size_t)N * ND * sizeof(float);
  float* e      = (float*)ws; ws += (size_t)E * ED * sizeof(float);
  float* agg    = (float*)ws; ws += (size_t)N * ED * sizeof(float);
  float* logits = (float*)ws; ws += (size_t)NC * sizeof(float);
  int*   seg    = (int*)ws;   ws += (size_t)NC * sizeof(int);
  unsigned int* mxu = (unsigned int*)ws; ws += (size_t)NG * sizeof(unsigned int);
  float* sum    = (float*)ws; ws += (size_t)NG * sizeof(float);

  const int* srcp = edge_index;
  const int* dstp = edge_index + E;

  const int blk = 256;
  k_init_h<<<(N * ND + blk - 1) / blk, blk, 0, stream>>>(x, Wn_in, bn_in, h, N);
  k_init_e<<<(E * ED + blk - 1) / blk, blk, 0, stream>>>(ea, We_in, be_in, e, E);

  for (int l = 0; l < NL; ++l) {
    hipMemsetAsync(agg, 0, (size_t)N * ED * sizeof(float), stream);
    k_edge<<<(E + blk - 1) / blk, blk, 0, stream>>>(
        h, e, srcp, dstp, We_l + (size_t)l * (2 * ND + ED) * ED,
        be_l + (size_t)l * ED, agg, E);
    k_node<<<(N + blk - 1) / blk, blk, 0, stream>>>(
        h, agg, Wn_l + (size_t)l * (ND + ED) * ND, bn_l + (size_t)l * ND, N);
  }

  hipMemsetAsync(mxu, 0, NG * sizeof(unsigned int), stream);
  hipMemsetAsync(sum, 0, NG * sizeof(float), stream);
  k_logits<<<(NC + blk - 1) / blk, blk, 0, stream>>>(h, cand, batch, Wout, bout,
                                                     logits, seg, mxu, NC);
  k_expsum<<<(NC + blk - 1) / blk, blk, 0, stream>>>(logits, seg, mxu, sum, NC);
  k_final<<<(NC + blk - 1) / blk, blk, 0, stream>>>(logits, seg, sum,
                                                    (float*)d_out, NC);
}

// Round 2
// 681.295 us; speedup vs baseline: 4.2292x; 4.2292x over previous
//
#include <hip/hip_runtime.h>

#define ND 32
#define ED 8
#define NL 4
#define NG 1000
#define SCAN_B 512

// ---------- init ----------

__global__ void k_init_h(const float* __restrict__ x,
                         const float* __restrict__ W,  // [2][ND]
                         const float* __restrict__ b,  // [ND]
                         float* __restrict__ h, int N) {
  int i = blockIdx.x * blockDim.x + threadIdx.x;
  if (i >= N * ND) return;
  int n = i >> 5, d = i & (ND - 1);
  h[i] = fmaf(x[2 * n], W[d], fmaf(x[2 * n + 1], W[ND + d], b[d]));
}

// ---------- CSR build (counting sort by dst) ----------

__global__ void k_hist(const int* __restrict__ dst, int* __restrict__ cnt, int E) {
  int i = blockIdx.x * blockDim.x + threadIdx.x;
  if (i < E) atomicAdd(&cnt[dst[i]], 1);
}

__global__ void k_blocksum(const int* __restrict__ cnt, int* __restrict__ bsum, int N) {
  __shared__ int s[SCAN_B];
  int i = blockIdx.x * SCAN_B + threadIdx.x;
  s[threadIdx.x] = (i < N) ? cnt[i] : 0;
  __syncthreads();
  for (int st = SCAN_B / 2; st > 0; st >>= 1) {
    if (threadIdx.x < (unsigned)st) s[threadIdx.x] += s[threadIdx.x + st];
    __syncthreads();
  }
  if (threadIdx.x == 0) bsum[blockIdx.x] = s[0];
}

// exclusive-scan the block sums (nb <= 1024 fast path via LDS)
__global__ void k_scan_bsums(int* __restrict__ bsum, int nb,
                             int* __restrict__ offsets, int N) {
  __shared__ int s[1024];
  __shared__ int tot;
  int tid = threadIdx.x;
  if (nb <= 1024) {
    for (int i = tid; i < nb; i += blockDim.x) s[i] = bsum[i];
    __syncthreads();
    if (tid == 0) {
      int run = 0;
      for (int i = 0; i < nb; ++i) { int v = s[i]; s[i] = run; run += v; }
      tot = run;
    }
    __syncthreads();
    for (int i = tid; i < nb; i += blockDim.x) bsum[i] = s[i];
    if (tid == 0) offsets[N] = tot;
  } else if (tid == 0) {
    int run = 0;
    for (int i = 0; i < nb; ++i) { int v = bsum[i]; bsum[i] = run; run += v; }
    offsets[N] = run;
  }
}

__global__ void k_scan_local(const int* __restrict__ cnt,
                             const int* __restrict__ bsum,
                             int* __restrict__ offsets, int N) {
  __shared__ int s[SCAN_B];
  int i = blockIdx.x * SCAN_B + threadIdx.x;
  int v = (i < N) ? cnt[i] : 0;
  s[threadIdx.x] = v;
  __syncthreads();
  for (int st = 1; st < SCAN_B; st <<= 1) {
    int t = (threadIdx.x >= (unsigned)st) ? s[threadIdx.x - st] : 0;
    __syncthreads();
    s[threadIdx.x] += t;
    __syncthreads();
  }
  if (i < N) offsets[i] = bsum[blockIdx.x] + s[threadIdx.x] - v;  // exclusive
}

// permute edges into dst-sorted order; also init e (sorted order) from edge_attr
__global__ void k_scatter(const int* __restrict__ src, const int* __restrict__ dst,
                          const float* __restrict__ ea,
                          const float* __restrict__ We,  // [ED]
                          const float* __restrict__ be,  // [ED]
                          const int* __restrict__ offsets, int* __restrict__ cursor,
                          int* __restrict__ ssrc, int* __restrict__ sdst,
                          float* __restrict__ e, int E) {
  __shared__ float sW[ED], sb[ED];
  if (threadIdx.x < ED) { sW[threadIdx.x] = We[threadIdx.x]; sb[threadIdx.x] = be[threadIdx.x]; }
  __syncthreads();
  int i = blockIdx.x * blockDim.x + threadIdx.x;
  if (i >= E) return;
  int d = dst[i];
  int pos = offsets[d] + atomicAdd(&cursor[d], 1);
  ssrc[pos] = src[i];
  sdst[pos] = d;
  float a = ea[i];
  float4 v0, v1;
  v0.x = fmaf(a, sW[0], sb[0]); v0.y = fmaf(a, sW[1], sb[1]);
  v0.z = fmaf(a, sW[2], sb[2]); v0.w = fmaf(a, sW[3], sb[3]);
  v1.x = fmaf(a, sW[4], sb[4]); v1.y = fmaf(a, sW[5], sb[5]);
  v1.z = fmaf(a, sW[6], sb[6]); v1.w = fmaf(a, sW[7], sb[7]);
  float4* e4 = reinterpret_cast<float4*>(e + (size_t)pos * ED);
  e4[0] = v0; e4[1] = v1;
}

// ---------- layer kernels ----------

__device__ __forceinline__ void acc4_ed(float4 v, const float* __restrict__ w,
                                        float* acc) {
#pragma unroll
  for (int j = 0; j < ED; ++j) acc[j] = fmaf(v.x, w[j], acc[j]);
#pragma unroll
  for (int j = 0; j < ED; ++j) acc[j] = fmaf(v.y, w[ED + j], acc[j]);
#pragma unroll
  for (int j = 0; j < ED; ++j) acc[j] = fmaf(v.z, w[2 * ED + j], acc[j]);
#pragma unroll
  for (int j = 0; j < ED; ++j) acc[j] = fmaf(v.w, w[3 * ED + j], acc[j]);
}

__device__ __forceinline__ void acc4_nd(float4 v, const float* __restrict__ w,
                                        float* acc) {
#pragma unroll
  for (int j = 0; j < ND; ++j) acc[j] = fmaf(v.x, w[j], acc[j]);
#pragma unroll
  for (int j = 0; j < ND; ++j) acc[j] = fmaf(v.y, w[ND + j], acc[j]);
#pragma unroll
  for (int j = 0; j < ND; ++j) acc[j] = fmaf(v.z, w[2 * ND + j], acc[j]);
#pragma unroll
  for (int j = 0; j < ND; ++j) acc[j] = fmaf(v.w, w[3 * ND + j], acc[j]);
}

// edge MLP over dst-sorted edges: ne = relu([h_s,h_d,e]@W+b); e += ne. No atomics.
__global__ void k_edge(const float* __restrict__ h,
                       float* __restrict__ e,
                       float* __restrict__ ne,
                       const int* __restrict__ ssrc,
                       const int* __restrict__ sdst,
                       const float* __restrict__ W,  // [(2*ND+ED)][ED]
                       const float* __restrict__ b,  // [ED]
                       int E) {
  __shared__ float sW[(2 * ND + ED) * ED];
  __shared__ float sb[ED];
  for (int i = threadIdx.x; i < (2 * ND + ED) * ED; i += blockDim.x) sW[i] = W[i];
  if (threadIdx.x < ED) sb[threadIdx.x] = b[threadIdx.x];
  __syncthreads();
  int i = blockIdx.x * blockDim.x + threadIdx.x;
  if (i >= E) return;
  int s = ssrc[i], d = sdst[i];
  float acc[ED];
#pragma unroll
  for (int j = 0; j < ED; ++j) acc[j] = sb[j];
  const float4* hs4 = reinterpret_cast<const float4*>(h + (size_t)s * ND);
  const float4* hd4 = reinterpret_cast<const float4*>(h + (size_t)d * ND);
#pragma unroll
  for (int q = 0; q < ND / 4; ++q) acc4_ed(hs4[q], &sW[q * 4 * ED], acc);
#pragma unroll
  for (int q = 0; q < ND / 4; ++q) acc4_ed(hd4[q], &sW[(ND + q * 4) * ED], acc);
  float4* e4 = reinterpret_cast<float4*>(e + (size_t)i * ED);
  float4 e0 = e4[0], e1 = e4[1];
  acc4_ed(e0, &sW[2 * ND * ED], acc);
  acc4_ed(e1, &sW[(2 * ND + 4) * ED], acc);
#pragma unroll
  for (int j = 0; j < ED; ++j) acc[j] = fmaxf(acc[j], 0.0f);
  float4* ne4 = reinterpret_cast<float4*>(ne + (size_t)i * ED);
  ne4[0] = make_float4(acc[0], acc[1], acc[2], acc[3]);
  ne4[1] = make_float4(acc[4], acc[5], acc[6], acc[7]);
  e4[0] = make_float4(e0.x + acc[0], e0.y + acc[1], e0.z + acc[2], e0.w + acc[3]);
  e4[1] = make_float4(e1.x + acc[4], e1.y + acc[5], e1.z + acc[6], e1.w + acc[7]);
}

// agg[n][j] = sum over CSR segment of ne rows; 8 threads per node
__global__ void k_agg(const float* __restrict__ ne,
                      const int* __restrict__ offsets,
                      float* __restrict__ agg, int N) {
  int t = blockIdx.x * blockDim.x + threadIdx.x;
  int n = t >> 3, j = t & (ED - 1);
  if (n >= N) return;
  int o0 = offsets[n], o1 = offsets[n + 1];
  float s = 0.0f;
  for (int k = o0; k < o1; ++k) s += ne[(size_t)k * ED + j];
  agg[(size_t)n * ED + j] = s;
}

// node MLP: h += relu([h, agg] @ W + b)
__global__ void k_node(float* __restrict__ h,
                       const float* __restrict__ agg,
                       const float* __restrict__ W,  // [(ND+ED)][ND]
                       const float* __restrict__ b,  // [ND]
                       int N) {
  __shared__ float sW[(ND + ED) * ND];
  __shared__ float sb[ND];
  for (int i = threadIdx.x; i < (ND + ED) * ND; i += blockDim.x) sW[i] = W[i];
  if (threadIdx.x < ND) sb[threadIdx.x] = b[threadIdx.x];
  __syncthreads();
  int n = blockIdx.x * blockDim.x + threadIdx.x;
  if (n >= N) return;
  float acc[ND];
#pragma unroll
  for (int j = 0; j < ND; ++j) acc[j] = sb[j];
  float4* h4 = reinterpret_cast<float4*>(h + (size_t)n * ND);
  float4 hv[ND / 4];
#pragma unroll
  for (int q = 0; q < ND / 4; ++q) {
    hv[q] = h4[q];
    acc4_nd(hv[q], &sW[q * 4 * ND], acc);
  }
  const float4* a4 = reinterpret_cast<const float4*>(agg + (size_t)n * ED);
#pragma unroll
  for (int q = 0; q < ED / 4; ++q) acc4_nd(a4[q], &sW[(ND + q * 4) * ND], acc);
#pragma unroll
  for (int q = 0; q < ND / 4; ++q) {
    float4 o;
    o.x = hv[q].x + fmaxf(acc[q * 4 + 0], 0.0f);
    o.y = hv[q].y + fmaxf(acc[q * 4 + 1], 0.0f);
    o.z = hv[q].z + fmaxf(acc[q * 4 + 2], 0.0f);
    o.w = hv[q].w + fmaxf(acc[q * 4 + 3], 0.0f);
    h4[q] = o;
  }
}

// ---------- readout ----------

__device__ __forceinline__ unsigned int enc_f32(float f) {
  unsigned int bits = __float_as_uint(f);
  return (bits & 0x80000000u) ? ~bits : (bits | 0x80000000u);
}
__device__ __forceinline__ float dec_f32(unsigned int u) {
  unsigned int bits = (u & 0x80000000u) ? (u ^ 0x80000000u) : ~u;
  return __uint_as_float(bits);
}

__global__ void k_logits(const float* __restrict__ h,
                         const int* __restrict__ cand,
                         const int* __restrict__ batch,
                         const float* __restrict__ Wout,  // [ND]
                         const float* __restrict__ bout,  // [1]
                         float* __restrict__ logits,
                         int* __restrict__ seg,
                         unsigned int* __restrict__ mxu,  // pre-zeroed
                         int NC) {
  __shared__ float sW[ND];
  if (threadIdx.x < ND) sW[threadIdx.x] = Wout[threadIdx.x];
  __syncthreads();
  int c = blockIdx.x * blockDim.x + threadIdx.x;
  if (c >= NC) return;
  int idx = cand[c];
  const float* hr = h + (size_t)idx * ND;
  float acc = bout[0];
#pragma unroll
  for (int k = 0; k < ND; ++k) acc = fmaf(hr[k], sW[k], acc);
  logits[c] = acc;
  int g = batch[idx];
  seg[c] = g;
  atomicMax(&mxu[g], enc_f32(acc));
}

__global__ void k_expsum(float* __restrict__ logits,
                         const int* __restrict__ seg,
                         const unsigned int* __restrict__ mxu,
                         float* __restrict__ sum,  // pre-zeroed
                         int NC) {
  int c = blockIdx.x * blockDim.x + threadIdx.x;
  if (c >= NC) return;
  int g = seg[c];
  float sh = logits[c] - dec_f32(mxu[g]);
  logits[c] = sh;
  atomicAdd(&sum[g], expf(sh));
}

__global__ void k_final(const float* __restrict__ shifted,
                        const int* __restrict__ seg,
                        const float* __restrict__ sum,
                        float* __restrict__ out, int NC) {
  int c = blockIdx.x * blockDim.x + threadIdx.x;
  if (c >= NC) return;
  out[c] = shifted[c] - logf(sum[seg[c]]);
}

// ---------- launch ----------

extern "C" void kernel_launch(void* const* d_in, const int* in_sizes, int n_in,
                              void* d_out, int out_size, void* d_ws, size_t ws_size,
                              hipStream_t stream) {
  const float* x       = (const float*)d_in[0];
  const float* ea      = (const float*)d_in[1];
  const float* Wn_in   = (const float*)d_in[2];
  const float* bn_in   = (const float*)d_in[3];
  const float* We_in   = (const float*)d_in[4];
  const float* be_in   = (const float*)d_in[5];
  const float* We_l    = (const float*)d_in[6];
  const float* be_l    = (const float*)d_in[7];
  const float* Wn_l    = (const float*)d_in[8];
  const float* bn_l    = (const float*)d_in[9];
  const float* Wout    = (const float*)d_in[10];
  const float* bout    = (const float*)d_in[11];
  const int* edge_index= (const int*)d_in[12];
  const int* batch     = (const int*)d_in[13];
  const int* cand      = (const int*)d_in[14];

  const int N  = in_sizes[13];
  const int E  = in_sizes[1];
  const int NC = in_sizes[14];
  const int nb = (N + SCAN_B - 1) / SCAN_B;

  char* ws = (char*)d_ws;
  float* h      = (float*)ws; ws += (size_t)N * ND * sizeof(float);
  float* e      = (float*)ws; ws += (size_t)E * ED * sizeof(float);
  float* ne     = (float*)ws; ws += (size_t)E * ED * sizeof(float);
  float* agg    = (float*)ws; ws += (size_t)N * ED * sizeof(float);
  int*   ssrc   = (int*)ws;   ws += (size_t)E * sizeof(int);
  int*   sdst   = (int*)ws;   ws += (size_t)E * sizeof(int);
  int*   cnt    = (int*)ws;   ws += (size_t)N * sizeof(int);
  int*   cursor = (int*)ws;   ws += (size_t)N * sizeof(int);
  int*   offs   = (int*)ws;   ws += ((size_t)N + 4) * sizeof(int);
  int*   bsum   = (int*)ws;   ws += 4096;
  float* logits = (float*)ws; ws += (size_t)NC * sizeof(float);
  int*   seg    = (int*)ws;   ws += (size_t)NC * sizeof(int);
  unsigned int* mxu = (unsigned int*)ws; ws += (size_t)NG * sizeof(unsigned int);
  float* sum    = (float*)ws; ws += (size_t)NG * sizeof(float);

  const int* srcp = edge_index;
  const int* dstp = edge_index + E;
  const int blk = 256;

  // CSR build
  hipMemsetAsync(cnt, 0, (size_t)N * sizeof(int), stream);
  hipMemsetAsync(cursor, 0, (size_t)N * sizeof(int), stream);
  k_hist<<<(E + blk - 1) / blk, blk, 0, stream>>>(dstp, cnt, E);
  k_blocksum<<<nb, SCAN_B, 0, stream>>>(cnt, bsum, N);
  k_scan_bsums<<<1, 1024, 0, stream>>>(bsum, nb, offs, N);
  k_scan_local<<<nb, SCAN_B, 0, stream>>>(cnt, bsum, offs, N);
  k_scatter<<<(E + blk - 1) / blk, blk, 0, stream>>>(
      srcp, dstp, ea, We_in, be_in, offs, cursor, ssrc, sdst, e, E);

  k_init_h<<<(N * ND + blk - 1) / blk, blk, 0, stream>>>(x, Wn_in, bn_in, h, N);

  for (int l = 0; l < NL; ++l) {
    k_edge<<<(E + blk - 1) / blk, blk, 0, stream>>>(
        h, e, ne, ssrc, sdst, We_l + (size_t)l * (2 * ND + ED) * ED,
        be_l + (size_t)l * ED, E);
    k_agg<<<((size_t)N * ED + blk - 1) / blk, blk, 0, stream>>>(ne, offs, agg, N);
    k_node<<<(N + blk - 1) / blk, blk, 0, stream>>>(
        h, agg, Wn_l + (size_t)l * (ND + ED) * ND, bn_l + (size_t)l * ND, N);
  }

  hipMemsetAsync(mxu, 0, NG * sizeof(unsigned int), stream);
  hipMemsetAsync(sum, 0, NG * sizeof(float), stream);
  k_logits<<<(NC + blk - 1) / blk, blk, 0, stream>>>(h, cand, batch, Wout, bout,
                                                     logits, seg, mxu, NC);
  k_expsum<<<(NC + blk - 1) / blk, blk, 0, stream>>>(logits, seg, mxu, sum, NC);
  k_final<<<(NC + blk - 1) / blk, blk, 0, stream>>>(logits, seg, sum,
                                                    (float*)d_out, NC);
}